// Round 4
// baseline (247.659 us; speedup 1.0000x reference)
//
#include <hip/hip_runtime.h>
#include <math.h>

// S4D via chunked linear-scan recurrence. x (L,B,D) f32, out (L,B,D) f32.
#define L_SEQ  4096
#define BSZ    4
#define DM     1024
#define NS     16
#define NCHUNK 64
#define CHUNK  (L_SEQ / NCHUNK)   // 64
#define LOG2_CHUNK 6
#define SCALE  0.25f
#define LBD    (BSZ * DM)         // 4096, x stride per l

// ws layout:
//   qbuf float2[NS*DM]            128 KiB   (indexed n*DM + d)
//   pbuf float2[NS*DM]            128 KiB
//   S    float2[BSZ*NCHUNK*NS*DM] 33.5 MiB  (indexed ((bc*NS)+n)*DM + d)

// ---------------------------------------------------------------- params
__global__ void s4d_params(const float* __restrict__ log_dt,
                           const float* __restrict__ log_A_real,
                           const float* __restrict__ A_imag,
                           const float* __restrict__ Bp,
                           const float* __restrict__ Cp,
                           float2* __restrict__ qbuf,
                           float2* __restrict__ pbuf) {
    int t = blockIdx.x * blockDim.x + threadIdx.x;   // t = n*DM + d
    if (t >= NS * DM) return;
    int n = t >> 10, d = t & (DM - 1);
    int i = d * NS + n;                              // input layout (D,N)
    float dt = expf(log_dt[d]);
    float Ar = -expf(log_A_real[i]);
    float Ai = A_imag[i];
    float ar = 0.5f * Ar * dt, ai = 0.5f * Ai * dt;  // dtA/2
    float den_r = 1.0f - ar, den_i = -ai;            // 1 - dtA/2
    float num_r = 1.0f + ar, num_i = ai;             // 1 + dtA/2
    float inv = 1.0f / (den_r * den_r + den_i * den_i);
    float qr = (num_r * den_r + num_i * den_i) * inv;
    float qi = (num_i * den_r - num_r * den_i) * inv;
    float B0 = Bp[2 * i], B1 = Bp[2 * i + 1];
    float C0 = Cp[2 * i], C1 = Cp[2 * i + 1];
    float ccr = B0 * C0 - B1 * C1;
    float cci = B0 * C1 + B1 * C0;
    float s = dt * inv * SCALE;
    float pr = (ccr * den_r + cci * den_i) * s;
    float pi = (cci * den_r - cci * 0.0f - ccr * den_i) * s;   // (cci*den_r - ccr*den_i)*s
    pbuf[t] = make_float2(pr, pi);
    qbuf[t] = make_float2(qr, qi);
}

// ---------------------------------------------------------------- pass 1
// One thread per (b,c,d): 16 states from h=0 over the chunk; store finals.
// 8-deep batched x loads for latency hiding. No min-waves bound: let the
// allocator keep all state in VGPRs (~85) -> 4 waves/SIMD, no accvgpr moves.
__global__ __launch_bounds__(256)
void s4d_pass1(const float* __restrict__ x,
               const float2* __restrict__ qbuf,
               float2* __restrict__ S) {
    int tid = blockIdx.x * 256 + threadIdx.x;        // BSZ*NCHUNK*DM threads
    int d  = tid & (DM - 1);
    int bc = tid >> 10;                              // b*NCHUNK + c
    int c  = bc & (NCHUNK - 1);
    int b  = bc >> LOG2_CHUNK;

    float qr[NS], qi[NS], hr[NS], hi[NS];
#pragma unroll
    for (int n = 0; n < NS; ++n) {
        float2 v = qbuf[n * DM + d];
        qr[n] = v.x; qi[n] = v.y; hr[n] = 0.0f; hi[n] = 0.0f;
    }
    const float* xp = x + (size_t)(c * CHUNK) * LBD + b * DM + d;
#pragma unroll
    for (int l0 = 0; l0 < CHUNK; l0 += 8) {
        float xv[8];
#pragma unroll
        for (int j = 0; j < 8; ++j)                  // 8 loads in flight
            xv[j] = xp[(size_t)(l0 + j) * LBD];
#pragma unroll
        for (int j = 0; j < 8; ++j) {
#pragma unroll
            for (int n = 0; n < NS; ++n) {
                float nr = fmaf(qr[n], hr[n], fmaf(-qi[n], hi[n], xv[j]));
                float ni = fmaf(qr[n], hi[n], qi[n] * hr[n]);
                hr[n] = nr; hi[n] = ni;
            }
        }
    }
    float2* sp = S + (size_t)bc * NS * DM + d;
#pragma unroll
    for (int n = 0; n < NS; ++n) sp[(size_t)n * DM] = make_float2(hr[n], hi[n]);
}

// ---------------------------------------------------------------- pass 2
// Inter-chunk scan in place, 8-deep static prefetch pipeline.
__global__ __launch_bounds__(256)
void s4d_pass2(const float2* __restrict__ qbuf,
               float2* __restrict__ S) {
    int tid = blockIdx.x * 256 + threadIdx.x;        // BSZ*DM*NS threads
    int d = tid & (DM - 1);
    int n = (tid >> 10) & (NS - 1);
    int b = tid >> 14;
    float2 qv = qbuf[n * DM + d];
    float qr = qv.x, qi = qv.y;
#pragma unroll
    for (int i = 0; i < LOG2_CHUNK; ++i) {           // q^CHUNK
        float nr = qr * qr - qi * qi;
        float ni = 2.0f * qr * qi;
        qr = nr; qi = ni;
    }
    size_t base = ((size_t)b * NCHUNK * NS + n) * DM + d;
    const size_t cs = (size_t)NS * DM;               // stride between chunks
    float hr = 0.0f, hi = 0.0f;
    float2 s0 = S[base + 0 * cs], s1 = S[base + 1 * cs],
           s2 = S[base + 2 * cs], s3 = S[base + 3 * cs],
           s4 = S[base + 4 * cs], s5 = S[base + 5 * cs],
           s6 = S[base + 6 * cs], s7 = S[base + 7 * cs];
#pragma unroll
    for (int c0 = 0; c0 < NCHUNK; c0 += 8) {
        float2 t0, t1, t2, t3, t4, t5, t6, t7;
        if (c0 + 8 < NCHUNK) {                       // static after unroll
            size_t nb2 = base + (size_t)(c0 + 8) * cs;
            t0 = S[nb2 + 0 * cs]; t1 = S[nb2 + 1 * cs];
            t2 = S[nb2 + 2 * cs]; t3 = S[nb2 + 3 * cs];
            t4 = S[nb2 + 4 * cs]; t5 = S[nb2 + 5 * cs];
            t6 = S[nb2 + 6 * cs]; t7 = S[nb2 + 7 * cs];
        }
#define STEP(J, SB)                                                      \
        {                                                                \
            S[base + (size_t)(c0 + J) * cs] = make_float2(hr, hi);       \
            float nr = fmaf(qr, hr, fmaf(-qi, hi, SB.x));                \
            float ni = fmaf(qr, hi, fmaf(qi, hr, SB.y));                 \
            hr = nr; hi = ni;                                            \
        }
        STEP(0, s0) STEP(1, s1) STEP(2, s2) STEP(3, s3)
        STEP(4, s4) STEP(5, s5) STEP(6, s6) STEP(7, s7)
#undef STEP
        if (c0 + 8 < NCHUNK) {
            s0 = t0; s1 = t1; s2 = t2; s3 = t3;
            s4 = t4; s5 = t5; s6 = t6; s7 = t7;
        }
    }
}

// ---------------------------------------------------------------- pass 3
// One thread per (b,c,d): replay 16 states from true incoming state;
// fuse residual + SiLU. 8-deep batched x loads.
__global__ __launch_bounds__(256)
void s4d_pass3(const float* __restrict__ x,
               const float* __restrict__ Dp,
               const float2* __restrict__ qbuf,
               const float2* __restrict__ pbuf,
               const float2* __restrict__ S,
               float* __restrict__ out) {
    int tid = blockIdx.x * 256 + threadIdx.x;
    int d  = tid & (DM - 1);
    int bc = tid >> 10;
    int c  = bc & (NCHUNK - 1);
    int b  = bc >> LOG2_CHUNK;

    float qr[NS], qi[NS], pr[NS], pi[NS], hr[NS], hi[NS];
#pragma unroll
    for (int n = 0; n < NS; ++n) {
        float2 v = qbuf[n * DM + d];
        float2 w = pbuf[n * DM + d];
        qr[n] = v.x; qi[n] = v.y; pr[n] = w.x; pi[n] = w.y;
    }
    const float2* sp = S + (size_t)bc * NS * DM + d;
#pragma unroll
    for (int n = 0; n < NS; ++n) {
        float2 s = sp[(size_t)n * DM];
        hr[n] = s.x; hi[n] = s.y;
    }
    float dpar = Dp[d];
    const float* xp = x + (size_t)(c * CHUNK) * LBD + b * DM + d;
    float* op = out + (size_t)(c * CHUNK) * LBD + b * DM + d;
#pragma unroll
    for (int l0 = 0; l0 < CHUNK; l0 += 8) {
        float xv[8];
#pragma unroll
        for (int j = 0; j < 8; ++j)                  // 8 loads in flight
            xv[j] = xp[(size_t)(l0 + j) * LBD];
#pragma unroll
        for (int j = 0; j < 8; ++j) {
            float acc = 0.0f;
#pragma unroll
            for (int n = 0; n < NS; ++n) {
                float nr = fmaf(qr[n], hr[n], fmaf(-qi[n], hi[n], xv[j]));
                float ni = fmaf(qr[n], hi[n], qi[n] * hr[n]);
                hr[n] = nr; hi[n] = ni;
                acc = fmaf(pr[n], nr, fmaf(-pi[n], ni, acc));
            }
            float z = fmaf(xv[j], dpar, acc);
            float sig = 1.0f / (1.0f + __expf(-z));
            op[(size_t)(l0 + j) * LBD] = z * sig;
        }
    }
}

// ---------------------------------------------------------------- launch
extern "C" void kernel_launch(void* const* d_in, const int* in_sizes, int n_in,
                              void* d_out, int out_size, void* d_ws, size_t ws_size,
                              hipStream_t stream) {
    const float* x          = (const float*)d_in[0];
    const float* log_dt     = (const float*)d_in[1];
    const float* log_A_real = (const float*)d_in[2];
    const float* A_imag     = (const float*)d_in[3];
    const float* Bp         = (const float*)d_in[4];
    const float* Cp         = (const float*)d_in[5];
    const float* Dp         = (const float*)d_in[6];
    float* out = (float*)d_out;

    float2* qbuf = (float2*)d_ws;
    float2* pbuf = qbuf + NS * DM;
    float2* S    = pbuf + NS * DM;

    hipLaunchKernelGGL(s4d_params, dim3((NS * DM) / 256), dim3(256), 0, stream,
                       log_dt, log_A_real, A_imag, Bp, Cp, qbuf, pbuf);
    hipLaunchKernelGGL(s4d_pass1, dim3((BSZ * NCHUNK * DM) / 256), dim3(256), 0, stream,
                       x, qbuf, S);
    hipLaunchKernelGGL(s4d_pass2, dim3((BSZ * DM * NS) / 256), dim3(256), 0, stream,
                       qbuf, S);
    hipLaunchKernelGGL(s4d_pass3, dim3((BSZ * NCHUNK * DM) / 256), dim3(256), 0, stream,
                       x, Dp, qbuf, pbuf, S, out);
}

// Round 5
// 206.277 us; speedup vs baseline: 1.2006x; 1.2006x over previous
//
#include <hip/hip_runtime.h>
#include <math.h>

// S4D via chunked linear-scan recurrence. x (L,B,D) f32, out (L,B,D) f32.
#define L_SEQ  4096
#define BSZ    4
#define DM     1024
#define NS     16
#define NSH    8                  // states per thread (n-split across wave halves)
#define NCHUNK 64
#define CHUNK  (L_SEQ / NCHUNK)   // 64
#define LOG2_CHUNK 6
#define SCALE  0.25f
#define LBD    (BSZ * DM)         // 4096, x stride per l

// ws layout:
//   qbuf float2[NS*DM]            128 KiB   (indexed n*DM + d)
//   pbuf float2[NS*DM]            128 KiB
//   S    float2[BSZ*NCHUNK*NS*DM] 33.5 MiB  (indexed ((bc*NS)+n)*DM + d)

// ---------------------------------------------------------------- params
__global__ void s4d_params(const float* __restrict__ log_dt,
                           const float* __restrict__ log_A_real,
                           const float* __restrict__ A_imag,
                           const float* __restrict__ Bp,
                           const float* __restrict__ Cp,
                           float2* __restrict__ qbuf,
                           float2* __restrict__ pbuf) {
    int t = blockIdx.x * blockDim.x + threadIdx.x;   // t = n*DM + d
    if (t >= NS * DM) return;
    int n = t >> 10, d = t & (DM - 1);
    int i = d * NS + n;                              // input layout (D,N)
    float dt = expf(log_dt[d]);
    float Ar = -expf(log_A_real[i]);
    float Ai = A_imag[i];
    float ar = 0.5f * Ar * dt, ai = 0.5f * Ai * dt;  // dtA/2
    float den_r = 1.0f - ar, den_i = -ai;            // 1 - dtA/2
    float num_r = 1.0f + ar, num_i = ai;             // 1 + dtA/2
    float inv = 1.0f / (den_r * den_r + den_i * den_i);
    float qr = (num_r * den_r + num_i * den_i) * inv;
    float qi = (num_i * den_r - num_r * den_i) * inv;
    float B0 = Bp[2 * i], B1 = Bp[2 * i + 1];
    float C0 = Cp[2 * i], C1 = Cp[2 * i + 1];
    float ccr = B0 * C0 - B1 * C1;
    float cci = B0 * C1 + B1 * C0;
    float s = dt * inv * SCALE;
    float pr = (ccr * den_r + cci * den_i) * s;
    float pi = (cci * den_r - ccr * den_i) * s;
    qbuf[t] = make_float2(qr, qi);
    pbuf[t] = make_float2(pr, pi);
}

// ---------------------------------------------------------------- pass 1
// 2 threads per (b,c,d), 8 states each, from h=0; store chunk-final states.
// xv[4] statically-indexed load batches for latency hiding.
__global__ __launch_bounds__(256, 4)
void s4d_pass1(const float* __restrict__ x,
               const float2* __restrict__ qbuf,
               float2* __restrict__ S) {
    int tid  = blockIdx.x * 256 + threadIdx.x;       // 2*BSZ*NCHUNK*DM threads
    int lane = tid & 63;
    int dlo  = lane & 31;
    int half = lane >> 5;
    int u    = tid >> 6;
    int dhi  = u & 31;
    int bc   = u >> 5;                               // b*NCHUNK + c
    int c    = bc & (NCHUNK - 1);
    int d    = dhi * 32 + dlo;
    int b    = bc >> LOG2_CHUNK;
    int nb   = half * NSH;

    float qr[NSH], qi[NSH], hr[NSH], hi[NSH];
#pragma unroll
    for (int j = 0; j < NSH; ++j) {
        float2 v = qbuf[(nb + j) * DM + d];
        qr[j] = v.x; qi[j] = v.y; hr[j] = 0.0f; hi[j] = 0.0f;
    }
    const float* xp = x + (size_t)(c * CHUNK) * LBD + b * DM + d;
#pragma unroll
    for (int l0 = 0; l0 < CHUNK; l0 += 4) {
        float xv[4];
#pragma unroll
        for (int j = 0; j < 4; ++j)                  // 4 loads in flight
            xv[j] = xp[(size_t)(l0 + j) * LBD];
#pragma unroll
        for (int j = 0; j < 4; ++j) {
#pragma unroll
            for (int n = 0; n < NSH; ++n) {
                float nr = fmaf(qr[n], hr[n], fmaf(-qi[n], hi[n], xv[j]));
                float ni = fmaf(qr[n], hi[n], qi[n] * hr[n]);
                hr[n] = nr; hi[n] = ni;
            }
        }
    }
    float2* sp = S + ((size_t)bc * NS + nb) * DM + d;
#pragma unroll
    for (int j = 0; j < NSH; ++j) sp[(size_t)j * DM] = make_float2(hr[j], hi[j]);
}

// ---------------------------------------------------------------- pass 2
// Inter-chunk scan in place, 8-deep static prefetch pipeline.
__global__ __launch_bounds__(256)
void s4d_pass2(const float2* __restrict__ qbuf,
               float2* __restrict__ S) {
    int tid = blockIdx.x * 256 + threadIdx.x;        // BSZ*DM*NS threads
    int d = tid & (DM - 1);
    int n = (tid >> 10) & (NS - 1);
    int b = tid >> 14;
    float2 qv = qbuf[n * DM + d];
    float qr = qv.x, qi = qv.y;
#pragma unroll
    for (int i = 0; i < LOG2_CHUNK; ++i) {           // q^CHUNK
        float nr = qr * qr - qi * qi;
        float ni = 2.0f * qr * qi;
        qr = nr; qi = ni;
    }
    size_t base = ((size_t)b * NCHUNK * NS + n) * DM + d;
    const size_t cs = (size_t)NS * DM;               // stride between chunks
    float hr = 0.0f, hi = 0.0f;
    float2 s0 = S[base + 0 * cs], s1 = S[base + 1 * cs],
           s2 = S[base + 2 * cs], s3 = S[base + 3 * cs],
           s4 = S[base + 4 * cs], s5 = S[base + 5 * cs],
           s6 = S[base + 6 * cs], s7 = S[base + 7 * cs];
#pragma unroll
    for (int c0 = 0; c0 < NCHUNK; c0 += 8) {
        float2 t0, t1, t2, t3, t4, t5, t6, t7;
        if (c0 + 8 < NCHUNK) {                       // static after unroll
            size_t nb2 = base + (size_t)(c0 + 8) * cs;
            t0 = S[nb2 + 0 * cs]; t1 = S[nb2 + 1 * cs];
            t2 = S[nb2 + 2 * cs]; t3 = S[nb2 + 3 * cs];
            t4 = S[nb2 + 4 * cs]; t5 = S[nb2 + 5 * cs];
            t6 = S[nb2 + 6 * cs]; t7 = S[nb2 + 7 * cs];
        }
#define STEP(J, SB)                                                      \
        {                                                                \
            S[base + (size_t)(c0 + J) * cs] = make_float2(hr, hi);       \
            float nr = fmaf(qr, hr, fmaf(-qi, hi, SB.x));                \
            float ni = fmaf(qr, hi, fmaf(qi, hr, SB.y));                 \
            hr = nr; hi = ni;                                            \
        }
        STEP(0, s0) STEP(1, s1) STEP(2, s2) STEP(3, s3)
        STEP(4, s4) STEP(5, s5) STEP(6, s6) STEP(7, s7)
#undef STEP
        if (c0 + 8 < NCHUNK) {
            s0 = t0; s1 = t1; s2 = t2; s3 = t3;
            s4 = t4; s5 = t5; s6 = t6; s7 = t7;
        }
    }
}

// ---------------------------------------------------------------- pass 3
// 2 threads per (b,c,d), 8 states each, replay from true incoming state;
// combine halves via shfl_xor(32); fast-math epilogue (v_exp + v_rcp).
__global__ __launch_bounds__(256, 4)
void s4d_pass3(const float* __restrict__ x,
               const float* __restrict__ Dp,
               const float2* __restrict__ qbuf,
               const float2* __restrict__ pbuf,
               const float2* __restrict__ S,
               float* __restrict__ out) {
    int tid  = blockIdx.x * 256 + threadIdx.x;
    int lane = tid & 63;
    int dlo  = lane & 31;
    int half = lane >> 5;
    int u    = tid >> 6;
    int dhi  = u & 31;
    int bc   = u >> 5;
    int c    = bc & (NCHUNK - 1);
    int d    = dhi * 32 + dlo;
    int b    = bc >> LOG2_CHUNK;
    int nb   = half * NSH;

    float qr[NSH], qi[NSH], pr[NSH], pi[NSH], hr[NSH], hi[NSH];
#pragma unroll
    for (int j = 0; j < NSH; ++j) {
        float2 v = qbuf[(nb + j) * DM + d];
        float2 w = pbuf[(nb + j) * DM + d];
        qr[j] = v.x; qi[j] = v.y; pr[j] = w.x; pi[j] = w.y;
    }
    const float2* sp = S + ((size_t)bc * NS + nb) * DM + d;
#pragma unroll
    for (int j = 0; j < NSH; ++j) {
        float2 s = sp[(size_t)j * DM];
        hr[j] = s.x; hi[j] = s.y;
    }
    float dpar = Dp[d];
    const float* xp = x + (size_t)(c * CHUNK) * LBD + b * DM + d;
    float* op = out + (size_t)(c * CHUNK) * LBD + b * DM + d;
#pragma unroll
    for (int l0 = 0; l0 < CHUNK; l0 += 4) {
        float xv[4];
#pragma unroll
        for (int j = 0; j < 4; ++j)                  // 4 loads in flight
            xv[j] = xp[(size_t)(l0 + j) * LBD];
#pragma unroll
        for (int j = 0; j < 4; ++j) {
            float acc = 0.0f;
#pragma unroll
            for (int n = 0; n < NSH; ++n) {
                float nr = fmaf(qr[n], hr[n], fmaf(-qi[n], hi[n], xv[j]));
                float ni = fmaf(qr[n], hi[n], qi[n] * hr[n]);
                hr[n] = nr; hi[n] = ni;
                acc = fmaf(pr[n], nr, fmaf(-pi[n], ni, acc));
            }
            acc += __shfl_xor(acc, 32, 64);          // combine n-halves
            float z = fmaf(xv[j], dpar, acc);
            float sig = __builtin_amdgcn_rcpf(1.0f + __expf(-z));
            if (half == 0) op[(size_t)(l0 + j) * LBD] = z * sig;
        }
    }
}

// ---------------------------------------------------------------- launch
extern "C" void kernel_launch(void* const* d_in, const int* in_sizes, int n_in,
                              void* d_out, int out_size, void* d_ws, size_t ws_size,
                              hipStream_t stream) {
    const float* x          = (const float*)d_in[0];
    const float* log_dt     = (const float*)d_in[1];
    const float* log_A_real = (const float*)d_in[2];
    const float* A_imag     = (const float*)d_in[3];
    const float* Bp         = (const float*)d_in[4];
    const float* Cp         = (const float*)d_in[5];
    const float* Dp         = (const float*)d_in[6];
    float* out = (float*)d_out;

    float2* qbuf = (float2*)d_ws;
    float2* pbuf = qbuf + NS * DM;
    float2* S    = pbuf + NS * DM;

    hipLaunchKernelGGL(s4d_params, dim3((NS * DM) / 256), dim3(256), 0, stream,
                       log_dt, log_A_real, A_imag, Bp, Cp, qbuf, pbuf);
    hipLaunchKernelGGL(s4d_pass1, dim3((2 * BSZ * NCHUNK * DM) / 256), dim3(256), 0, stream,
                       x, qbuf, S);
    hipLaunchKernelGGL(s4d_pass2, dim3((BSZ * DM * NS) / 256), dim3(256), 0, stream,
                       qbuf, S);
    hipLaunchKernelGGL(s4d_pass3, dim3((2 * BSZ * NCHUNK * DM) / 256), dim3(256), 0, stream,
                       x, Dp, qbuf, pbuf, S, out);
}

// Round 6
// 192.350 us; speedup vs baseline: 1.2875x; 1.0724x over previous
//
#include <hip/hip_runtime.h>
#include <math.h>

// S4D via chunked linear-scan recurrence. x (L,B,D) f32, out (L,B,D) f32.
#define L_SEQ  4096
#define BSZ    4
#define DM     1024
#define NS     16
#define NSH    8                  // states per thread (n-split across wave halves)
#define NCHUNK 64
#define CHUNK  (L_SEQ / NCHUNK)   // 64
#define LOG2_CHUNK 6
#define SCALE  0.25f
#define LBD    (BSZ * DM)         // 4096, x stride per l

// ws layout:
//   qbuf float2[NS*DM]            128 KiB   (indexed n*DM + d)
//   pbuf float2[NS*DM]            128 KiB
//   S    float2[BSZ*NCHUNK*NS*DM] 33.5 MiB  (indexed ((bc*NS)+n)*DM + d)

// ---------------------------------------------------------------- params
__global__ void s4d_params(const float* __restrict__ log_dt,
                           const float* __restrict__ log_A_real,
                           const float* __restrict__ A_imag,
                           const float* __restrict__ Bp,
                           const float* __restrict__ Cp,
                           float2* __restrict__ qbuf,
                           float2* __restrict__ pbuf) {
    int t = blockIdx.x * blockDim.x + threadIdx.x;   // t = n*DM + d
    if (t >= NS * DM) return;
    int n = t >> 10, d = t & (DM - 1);
    int i = d * NS + n;                              // input layout (D,N)
    float dt = expf(log_dt[d]);
    float Ar = -expf(log_A_real[i]);
    float Ai = A_imag[i];
    float ar = 0.5f * Ar * dt, ai = 0.5f * Ai * dt;  // dtA/2
    float den_r = 1.0f - ar, den_i = -ai;            // 1 - dtA/2
    float num_r = 1.0f + ar, num_i = ai;             // 1 + dtA/2
    float inv = 1.0f / (den_r * den_r + den_i * den_i);
    float qr = (num_r * den_r + num_i * den_i) * inv;
    float qi = (num_i * den_r - num_r * den_i) * inv;
    float B0 = Bp[2 * i], B1 = Bp[2 * i + 1];
    float C0 = Cp[2 * i], C1 = Cp[2 * i + 1];
    float ccr = B0 * C0 - B1 * C1;
    float cci = B0 * C1 + B1 * C0;
    float s = dt * inv * SCALE;
    float pr = (ccr * den_r + cci * den_i) * s;
    float pi = (cci * den_r - ccr * den_i) * s;
    qbuf[t] = make_float2(qr, qi);
    pbuf[t] = make_float2(pr, pi);
}

// ---------------------------------------------------------------- pass 1
// 2 threads per (b,c,d), 8 states each, from h=0; store chunk-final states.
// waves_per_eu(4,4): pin occupancy target -> 128-VGPR budget -> no AGPR spill.
__attribute__((amdgpu_waves_per_eu(4, 4)))
__global__ __launch_bounds__(256)
void s4d_pass1(const float* __restrict__ x,
               const float2* __restrict__ qbuf,
               float2* __restrict__ S) {
    int tid  = blockIdx.x * 256 + threadIdx.x;       // 2*BSZ*NCHUNK*DM threads
    int lane = tid & 63;
    int dlo  = lane & 31;
    int half = lane >> 5;
    int u    = tid >> 6;
    int dhi  = u & 31;
    int bc   = u >> 5;                               // b*NCHUNK + c
    int c    = bc & (NCHUNK - 1);
    int d    = dhi * 32 + dlo;
    int b    = bc >> LOG2_CHUNK;
    int nb   = half * NSH;

    float qr[NSH], qi[NSH], hr[NSH], hi[NSH];
#pragma unroll
    for (int j = 0; j < NSH; ++j) {
        float2 v = qbuf[(nb + j) * DM + d];
        qr[j] = v.x; qi[j] = v.y; hr[j] = 0.0f; hi[j] = 0.0f;
    }
    const float* xp = x + (size_t)(c * CHUNK) * LBD + b * DM + d;
#pragma unroll
    for (int l0 = 0; l0 < CHUNK; l0 += 4) {
        float xv0 = xp[(size_t)(l0 + 0) * LBD];
        float xv1 = xp[(size_t)(l0 + 1) * LBD];
        float xv2 = xp[(size_t)(l0 + 2) * LBD];
        float xv3 = xp[(size_t)(l0 + 3) * LBD];
#define P1STEP(XV)                                                       \
        {                                                                \
            _Pragma("unroll")                                            \
            for (int n = 0; n < NSH; ++n) {                              \
                float nr = fmaf(qr[n], hr[n], fmaf(-qi[n], hi[n], XV));  \
                float ni = fmaf(qr[n], hi[n], qi[n] * hr[n]);            \
                hr[n] = nr; hi[n] = ni;                                  \
            }                                                            \
        }
        P1STEP(xv0) P1STEP(xv1) P1STEP(xv2) P1STEP(xv3)
#undef P1STEP
    }
    float2* sp = S + ((size_t)bc * NS + nb) * DM + d;
#pragma unroll
    for (int j = 0; j < NSH; ++j) sp[(size_t)j * DM] = make_float2(hr[j], hi[j]);
}

// ---------------------------------------------------------------- pass 2
// Inter-chunk scan in place, 8-deep static prefetch pipeline.
__global__ __launch_bounds__(256)
void s4d_pass2(const float2* __restrict__ qbuf,
               float2* __restrict__ S) {
    int tid = blockIdx.x * 256 + threadIdx.x;        // BSZ*DM*NS threads
    int d = tid & (DM - 1);
    int n = (tid >> 10) & (NS - 1);
    int b = tid >> 14;
    float2 qv = qbuf[n * DM + d];
    float qr = qv.x, qi = qv.y;
#pragma unroll
    for (int i = 0; i < LOG2_CHUNK; ++i) {           // q^CHUNK
        float nr = qr * qr - qi * qi;
        float ni = 2.0f * qr * qi;
        qr = nr; qi = ni;
    }
    size_t base = ((size_t)b * NCHUNK * NS + n) * DM + d;
    const size_t cs = (size_t)NS * DM;               // stride between chunks
    float hr = 0.0f, hi = 0.0f;
    float2 s0 = S[base + 0 * cs], s1 = S[base + 1 * cs],
           s2 = S[base + 2 * cs], s3 = S[base + 3 * cs],
           s4 = S[base + 4 * cs], s5 = S[base + 5 * cs],
           s6 = S[base + 6 * cs], s7 = S[base + 7 * cs];
#pragma unroll
    for (int c0 = 0; c0 < NCHUNK; c0 += 8) {
        float2 t0, t1, t2, t3, t4, t5, t6, t7;
        if (c0 + 8 < NCHUNK) {                       // static after unroll
            size_t nb2 = base + (size_t)(c0 + 8) * cs;
            t0 = S[nb2 + 0 * cs]; t1 = S[nb2 + 1 * cs];
            t2 = S[nb2 + 2 * cs]; t3 = S[nb2 + 3 * cs];
            t4 = S[nb2 + 4 * cs]; t5 = S[nb2 + 5 * cs];
            t6 = S[nb2 + 6 * cs]; t7 = S[nb2 + 7 * cs];
        }
#define STEP(J, SB)                                                      \
        {                                                                \
            S[base + (size_t)(c0 + J) * cs] = make_float2(hr, hi);       \
            float nr = fmaf(qr, hr, fmaf(-qi, hi, SB.x));                \
            float ni = fmaf(qr, hi, fmaf(qi, hr, SB.y));                 \
            hr = nr; hi = ni;                                            \
        }
        STEP(0, s0) STEP(1, s1) STEP(2, s2) STEP(3, s3)
        STEP(4, s4) STEP(5, s5) STEP(6, s6) STEP(7, s7)
#undef STEP
        if (c0 + 8 < NCHUNK) {
            s0 = t0; s1 = t1; s2 = t2; s3 = t3;
            s4 = t4; s5 = t5; s6 = t6; s7 = t7;
        }
    }
}

// ---------------------------------------------------------------- pass 3
// 2 threads per (b,c,d), 8 states each, replay from true incoming state;
// 4-step batches: 4 loads in flight, 4 back-to-back shfls, 4 epilogues.
__attribute__((amdgpu_waves_per_eu(4, 4)))
__global__ __launch_bounds__(256)
void s4d_pass3(const float* __restrict__ x,
               const float* __restrict__ Dp,
               const float2* __restrict__ qbuf,
               const float2* __restrict__ pbuf,
               const float2* __restrict__ S,
               float* __restrict__ out) {
    int tid  = blockIdx.x * 256 + threadIdx.x;
    int lane = tid & 63;
    int dlo  = lane & 31;
    int half = lane >> 5;
    int u    = tid >> 6;
    int dhi  = u & 31;
    int bc   = u >> 5;
    int c    = bc & (NCHUNK - 1);
    int d    = dhi * 32 + dlo;
    int b    = bc >> LOG2_CHUNK;
    int nb   = half * NSH;

    float qr[NSH], qi[NSH], pr[NSH], pi[NSH], hr[NSH], hi[NSH];
#pragma unroll
    for (int j = 0; j < NSH; ++j) {
        float2 v = qbuf[(nb + j) * DM + d];
        float2 w = pbuf[(nb + j) * DM + d];
        qr[j] = v.x; qi[j] = v.y; pr[j] = w.x; pi[j] = w.y;
    }
    const float2* sp = S + ((size_t)bc * NS + nb) * DM + d;
#pragma unroll
    for (int j = 0; j < NSH; ++j) {
        float2 s = sp[(size_t)j * DM];
        hr[j] = s.x; hi[j] = s.y;
    }
    float dpar = Dp[d];
    const float* xp = x + (size_t)(c * CHUNK) * LBD + b * DM + d;
    float* op = out + (size_t)(c * CHUNK) * LBD + b * DM + d;
#pragma unroll
    for (int l0 = 0; l0 < CHUNK; l0 += 4) {
        float xv0 = xp[(size_t)(l0 + 0) * LBD];
        float xv1 = xp[(size_t)(l0 + 1) * LBD];
        float xv2 = xp[(size_t)(l0 + 2) * LBD];
        float xv3 = xp[(size_t)(l0 + 3) * LBD];
        float acc0, acc1, acc2, acc3;
#define P3STEP(XV, ACC)                                                  \
        {                                                                \
            float a = 0.0f;                                              \
            _Pragma("unroll")                                            \
            for (int n = 0; n < NSH; ++n) {                              \
                float nr = fmaf(qr[n], hr[n], fmaf(-qi[n], hi[n], XV));  \
                float ni = fmaf(qr[n], hi[n], qi[n] * hr[n]);            \
                hr[n] = nr; hi[n] = ni;                                  \
                a = fmaf(pr[n], nr, fmaf(-pi[n], ni, a));                \
            }                                                            \
            ACC = a;                                                     \
        }
        P3STEP(xv0, acc0) P3STEP(xv1, acc1) P3STEP(xv2, acc2) P3STEP(xv3, acc3)
#undef P3STEP
        acc0 += __shfl_xor(acc0, 32, 64);            // combine n-halves
        acc1 += __shfl_xor(acc1, 32, 64);
        acc2 += __shfl_xor(acc2, 32, 64);
        acc3 += __shfl_xor(acc3, 32, 64);
        float z0 = fmaf(xv0, dpar, acc0);
        float z1 = fmaf(xv1, dpar, acc1);
        float z2 = fmaf(xv2, dpar, acc2);
        float z3 = fmaf(xv3, dpar, acc3);
        float r0 = z0 * __builtin_amdgcn_rcpf(1.0f + __expf(-z0));
        float r1 = z1 * __builtin_amdgcn_rcpf(1.0f + __expf(-z1));
        float r2 = z2 * __builtin_amdgcn_rcpf(1.0f + __expf(-z2));
        float r3 = z3 * __builtin_amdgcn_rcpf(1.0f + __expf(-z3));
        if (half == 0) {
            op[(size_t)(l0 + 0) * LBD] = r0;
            op[(size_t)(l0 + 1) * LBD] = r1;
            op[(size_t)(l0 + 2) * LBD] = r2;
            op[(size_t)(l0 + 3) * LBD] = r3;
        }
    }
}

// ---------------------------------------------------------------- launch
extern "C" void kernel_launch(void* const* d_in, const int* in_sizes, int n_in,
                              void* d_out, int out_size, void* d_ws, size_t ws_size,
                              hipStream_t stream) {
    const float* x          = (const float*)d_in[0];
    const float* log_dt     = (const float*)d_in[1];
    const float* log_A_real = (const float*)d_in[2];
    const float* A_imag     = (const float*)d_in[3];
    const float* Bp         = (const float*)d_in[4];
    const float* Cp         = (const float*)d_in[5];
    const float* Dp         = (const float*)d_in[6];
    float* out = (float*)d_out;

    float2* qbuf = (float2*)d_ws;
    float2* pbuf = qbuf + NS * DM;
    float2* S    = pbuf + NS * DM;

    hipLaunchKernelGGL(s4d_params, dim3((NS * DM) / 256), dim3(256), 0, stream,
                       log_dt, log_A_real, A_imag, Bp, Cp, qbuf, pbuf);
    hipLaunchKernelGGL(s4d_pass1, dim3((2 * BSZ * NCHUNK * DM) / 256), dim3(256), 0, stream,
                       x, qbuf, S);
    hipLaunchKernelGGL(s4d_pass2, dim3((BSZ * DM * NS) / 256), dim3(256), 0, stream,
                       qbuf, S);
    hipLaunchKernelGGL(s4d_pass3, dim3((2 * BSZ * NCHUNK * DM) / 256), dim3(256), 0, stream,
                       x, Dp, qbuf, pbuf, S, out);
}